// Round 20
// baseline (225.822 us; speedup 1.0000x reference)
//
#include <hip/hip_runtime.h>
#include <hip/hip_bf16.h>
#include <math.h>

#define TOK  4096
#define DM   1024
#define DKC  1024
#define DVC  2048
#define NH   4
#define HDK_ 256
#define HDV_ 512
#define NCH  32
#define CHK  64

typedef __attribute__((ext_vector_type(8))) short bf16x8;
typedef __attribute__((ext_vector_type(4))) float f32x4;

__device__ inline float bf2f(short s) {
    unsigned int b = ((unsigned int)(unsigned short)s) << 16;
    return __uint_as_float(b);
}
__device__ inline short f2bf_bits(float f) {
    __hip_bfloat16 h = __float2bfloat16(f);
    return *reinterpret_cast<short*>(&h);
}

// async global->LDS, 16B per lane; lds dest = base + lane*16 (wave-uniform base)
__device__ __forceinline__ void gl_lds16(const void* g, void* l) {
    __builtin_amdgcn_global_load_lds((const __attribute__((address_space(1))) void*)g,
                                     (__attribute__((address_space(3))) void*)l, 16, 0, 0);
}

// ---------------------------------------------------------------------------
// prep_all: fused weight transposes (bid<8192) + x-path (bid>=8192).
// ---------------------------------------------------------------------------
__global__ __launch_bounds__(256) void prep_all(const float* __restrict__ Wq,
                                                const float* __restrict__ Wk,
                                                const float* __restrict__ Wv,
                                                const float* __restrict__ Wg,
                                                const float* __restrict__ Wo,
                                                __hip_bfloat16* __restrict__ WtAll,
                                                __hip_bfloat16* __restrict__ WtO,
                                                const float* __restrict__ x,
                                                const float* __restrict__ W1,
                                                const float* __restrict__ W2,
                                                const float* __restrict__ b2,
                                                __hip_bfloat16* __restrict__ xb,
                                                float* __restrict__ g) {
    const int bid = blockIdx.x;
    const int tid = threadIdx.x;
    if (bid < 8192) {
        __shared__ float tile[32][33];
        const float* W; __hip_bfloat16* Wt; int K, N, r;
        if (bid < 1024)      { W = Wq; Wt = WtAll;               K = 1024; N = 1024; r = bid; }
        else if (bid < 2048) { W = Wk; Wt = WtAll + 1024 * 1024; K = 1024; N = 1024; r = bid - 1024; }
        else if (bid < 4096) { W = Wv; Wt = WtAll + 2048 * 1024; K = 1024; N = 2048; r = bid - 2048; }
        else if (bid < 6144) { W = Wg; Wt = WtAll + 4096 * 1024; K = 1024; N = 2048; r = bid - 4096; }
        else                 { W = Wo; Wt = WtO;                 K = 2048; N = 1024; r = bid - 6144; }
        const int ncols = N >> 5;
        const int n0 = (r % ncols) * 32, k0 = (r / ncols) * 32;
        const int tx = tid & 31, ty = tid >> 5;
#pragma unroll
        for (int i = 0; i < 32; i += 8)
            tile[ty + i][tx] = W[(size_t)(k0 + ty + i) * N + n0 + tx];
        __syncthreads();
#pragma unroll
        for (int i = 0; i < 32; i += 8)
            Wt[(size_t)(n0 + ty + i) * K + k0 + tx] = __float2bfloat16(tile[tx][ty + i]);
    } else {
        __shared__ float xl[1024];
        __shared__ float red[16][17];
        __shared__ float t1l[16];
        const int t = bid - 8192;
        float4 xv = *reinterpret_cast<const float4*>(&x[(size_t)t * DM + tid * 4]);
        *reinterpret_cast<float4*>(&xl[tid * 4]) = xv;
        short4 xs;
        xs.x = f2bf_bits(xv.x); xs.y = f2bf_bits(xv.y);
        xs.z = f2bf_bits(xv.z); xs.w = f2bf_bits(xv.w);
        *reinterpret_cast<short4*>((short*)xb + (size_t)t * DM + tid * 4) = xs;
        __syncthreads();
        const int o = tid & 15, p = tid >> 4;
        float s = 0.f;
#pragma unroll 8
        for (int m = 0; m < 64; ++m) {
            int kk = p * 64 + m;
            s += xl[kk] * W1[kk * 16 + o];
        }
        red[p][o] = s;
        __syncthreads();
        if (tid < 16) {
            float tot = 0.f;
#pragma unroll
            for (int pp = 0; pp < 16; ++pp) tot += red[pp][tid];
            t1l[tid] = tot;
        }
        __syncthreads();
#pragma unroll
        for (int j = 0; j < 4; ++j) {
            int c = tid + j * 256;
            float acc = b2[c];
#pragma unroll
            for (int r2 = 0; r2 < 16; ++r2) acc += t1l[r2] * W2[r2 * 1024 + c];
            float ls = fminf(acc, 0.f) - log1pf(expf(-fabsf(acc)));
            g[(size_t)t * DKC + c] = ls * (1.f / 16.f);
        }
    }
}

// ---------------------------------------------------------------------------
// FUSED projection GEMM, 128x256 tile, 512 thr (8 waves 2Mx4N), BK=64.
// (converged schedule — do not modify)
// ---------------------------------------------------------------------------
__global__ __launch_bounds__(512) void gemm256(const __hip_bfloat16* __restrict__ A,
                                               const __hip_bfloat16* __restrict__ Wt,
                                               __hip_bfloat16* __restrict__ qo,
                                               __hip_bfloat16* __restrict__ ko,
                                               __hip_bfloat16* __restrict__ vT,
                                               __hip_bfloat16* __restrict__ xgo) {
    __shared__ __align__(16) short SM[9 * 8192];   // 144 KB ring
    const int K = 1024, NT = 16;
    const int tid = threadIdx.x;
    const int wave = tid >> 6, lane = tid & 63;
    const int wr = wave >> 2;        // M half (0..1)
    const int wc = wave & 3;         // N quarter (0..3)
    const int hc = wc >> 1;          // B unit (lo/hi 128)
    const int l15 = lane & 15, kb = lane >> 4;
    const int m0 = blockIdx.y * 128, n0 = blockIdx.x * 256;

    const bool isV = (n0 >= 2048 && n0 < 4096);
    __hip_bfloat16* dst = nullptr; int ldd = 0, nloc0 = 0;
    if (n0 < 1024)       { dst = qo;  ldd = 1024; nloc0 = n0; }
    else if (n0 < 2048)  { dst = ko;  ldd = 1024; nloc0 = n0 - 1024; }
    else if (n0 >= 4096) { dst = xgo; ldd = 2048; nloc0 = n0 - 4096; }

    f32x4 acc[4][4];
#pragma unroll
    for (int mf = 0; mf < 4; ++mf)
#pragma unroll
        for (int nf = 0; nf < 4; ++nf) acc[mf][nf] = (f32x4){0.f, 0.f, 0.f, 0.f};

    auto stage_unit = [&](int u) {
        int tk = u / 3, p = u % 3;
        int slot = u % 9;
#pragma unroll
        for (int j = 0; j < 2; ++j) {
            int row = (wave * 2 + j) * 8 + (lane >> 3);   // 0..127
            int srcg = (lane & 7) ^ (row & 7);
            const __hip_bfloat16* src =
                (p == 0) ? &A[(size_t)(m0 + row) * K + tk * 64 + srcg * 8]
                         : &Wt[(size_t)(n0 + (p - 1) * 128 + row) * K + tk * 64 + srcg * 8];
            gl_lds16(src, &SM[slot * 8192 + (wave * 2 + j) * 512]);
        }
    };

    for (int u = 0; u <= 5; ++u) stage_unit(u);

    const int ULAST = 3 * NT - 1;
    for (int t = 0; t < NT; ++t) {
        if (t < NT - 1) asm volatile("s_waitcnt vmcnt(6)" ::: "memory");
        else            asm volatile("s_waitcnt vmcnt(0)" ::: "memory");
        __builtin_amdgcn_sched_barrier(0);
        __builtin_amdgcn_s_barrier();

        if (3 * t + 6 <= ULAST) stage_unit(3 * t + 6);
        if (3 * t + 7 <= ULAST) stage_unit(3 * t + 7);
        if (3 * t + 8 <= ULAST) stage_unit(3 * t + 8);
        __builtin_amdgcn_sched_barrier(0);

        const short* Abase = &SM[((3 * t) % 9) * 8192];
        const short* Bbase = &SM[((3 * t + 1 + hc) % 9) * 8192];

        bf16x8 a0[4], b0[4], a1[4], b1[4];
#pragma unroll
        for (int mf = 0; mf < 4; ++mf) {
            int row = wr * 64 + mf * 16 + l15;
            a0[mf] = *reinterpret_cast<const bf16x8*>(&Abase[row * 64 + (kb ^ (row & 7)) * 8]);
        }
#pragma unroll
        for (int nf = 0; nf < 4; ++nf) {
            int row = (wc & 1) * 64 + nf * 16 + l15;
            b0[nf] = *reinterpret_cast<const bf16x8*>(&Bbase[row * 64 + (kb ^ (row & 7)) * 8]);
        }
        __builtin_amdgcn_sched_barrier(0);
#pragma unroll
        for (int mf = 0; mf < 4; ++mf) {
            int row = wr * 64 + mf * 16 + l15;
            a1[mf] = *reinterpret_cast<const bf16x8*>(&Abase[row * 64 + ((4 + kb) ^ (row & 7)) * 8]);
        }
#pragma unroll
        for (int nf = 0; nf < 4; ++nf) {
            int row = (wc & 1) * 64 + nf * 16 + l15;
            b1[nf] = *reinterpret_cast<const bf16x8*>(&Bbase[row * 64 + ((4 + kb) ^ (row & 7)) * 8]);
        }
        __builtin_amdgcn_sched_barrier(0);
        asm volatile("s_waitcnt lgkmcnt(8)" ::: "memory");
        __builtin_amdgcn_sched_barrier(0);
        __builtin_amdgcn_s_setprio(1);
#pragma unroll
        for (int mf = 0; mf < 4; ++mf)
#pragma unroll
            for (int nf = 0; nf < 4; ++nf)
                acc[mf][nf] = __builtin_amdgcn_mfma_f32_16x16x32_bf16(a0[mf], b0[nf], acc[mf][nf], 0, 0, 0);
        __builtin_amdgcn_s_setprio(0);
        asm volatile("s_waitcnt lgkmcnt(0)" ::: "memory");
        __builtin_amdgcn_sched_barrier(0);
        __builtin_amdgcn_s_setprio(1);
#pragma unroll
        for (int mf = 0; mf < 4; ++mf)
#pragma unroll
            for (int nf = 0; nf < 4; ++nf)
                acc[mf][nf] = __builtin_amdgcn_mfma_f32_16x16x32_bf16(a1[mf], b1[nf], acc[mf][nf], 0, 0, 0);
        __builtin_amdgcn_s_setprio(0);
    }

    if (!isV) {
#pragma unroll
        for (int mf = 0; mf < 4; ++mf)
#pragma unroll
            for (int nf = 0; nf < 4; ++nf)
#pragma unroll
                for (int r = 0; r < 4; ++r)
                    dst[(size_t)(m0 + wr * 64 + mf * 16 + kb * 4 + r) * ldd +
                        nloc0 + wc * 64 + nf * 16 + l15] = __float2bfloat16(acc[mf][nf][r]);
    } else {
        __syncthreads();
        short* Cl = SM;                  // [256 vc][132] shorts
#pragma unroll
        for (int mf = 0; mf < 4; ++mf)
#pragma unroll
            for (int nf = 0; nf < 4; ++nf)
#pragma unroll
                for (int r = 0; r < 4; ++r) {
                    int trow = wr * 64 + mf * 16 + kb * 4 + r;      // 0..127
                    int vcol = wc * 64 + nf * 16 + l15;             // 0..255
                    Cl[vcol * 132 + trow] = f2bf_bits(acc[mf][nf][r]);
                }
        __syncthreads();
        const int vcg0 = n0 - 2048;
        const int bh = (m0 >> 11) * NH + (vcg0 >> 9);
        const int vl0 = vcg0 & 511;
        const int tl0 = m0 & 2047;
        short* vTs = (short*)vT;
#pragma unroll
        for (int it = 0; it < 8; ++it) {
            int idx = tid + it * 512;    // 0..4095
            int row = idx >> 4;          // 0..255
            int c8 = (idx & 15) * 8;     // 0..120
            bf16x8 vv = *reinterpret_cast<const bf16x8*>(&Cl[row * 132 + c8]);
            *reinterpret_cast<bf16x8*>(
                &vTs[((size_t)(bh * 512 + vl0 + row)) * 2048 + tl0 + c8]) = vv;
        }
    }
}

// ---------------------------------------------------------------------------
// Double-buffered bf16 MFMA GEMM, f32 C (final Wo projection).
// ---------------------------------------------------------------------------
__global__ __launch_bounds__(256) void gemm_bf16(const __hip_bfloat16* __restrict__ A,
                                                 const __hip_bfloat16* __restrict__ Wt,
                                                 float* __restrict__ C,
                                                 int M, int N, int K) {
    __shared__ __align__(16) short Buf[2][2][128 * 64];   // [dbuf][A/B] 64 KB
    const int tid = threadIdx.x;
    const int wave = tid >> 6, lane = tid & 63;
    const int wr = wave >> 1, wc = wave & 1;
    const int m0 = blockIdx.y * 128, n0 = blockIdx.x * 128;
    const int l15 = lane & 15, kb = lane >> 4;
    const int lr8 = lane >> 3, lc8 = (lane & 7) * 8;
    const int NT = K >> 6;

    f32x4 acc[4][4];
#pragma unroll
    for (int mf = 0; mf < 4; ++mf)
#pragma unroll
        for (int nf = 0; nf < 4; ++nf) acc[mf][nf] = (f32x4){0.f, 0.f, 0.f, 0.f};

#define STAGE_G(kt, bi)                                                          \
    {                                                                            \
        int k0s = (kt) * 64;                                                     \
        _Pragma("unroll")                                                        \
        for (int j = 0; j < 4; ++j) {                                            \
            int inst = wave * 4 + j;                                             \
            int r = inst * 8 + lr8;                                              \
            gl_lds16(&A[(size_t)(m0 + r) * K + k0s + lc8], &Buf[bi][0][inst * 512]); \
            gl_lds16(&Wt[(size_t)(n0 + r) * K + k0s + lc8], &Buf[bi][1][inst * 512]); \
        }                                                                        \
    }

    STAGE_G(0, 0);
    STAGE_G(1, 1);

    for (int t = 0; t < NT; ++t) {
        if (t + 1 < NT) asm volatile("s_waitcnt vmcnt(8)" ::: "memory");
        else            asm volatile("s_waitcnt vmcnt(0)" ::: "memory");
        __builtin_amdgcn_sched_barrier(0);
        __builtin_amdgcn_s_barrier();
        const short* Ab = Buf[t & 1][0];
        const short* Bb = Buf[t & 1][1];
        bf16x8 a0[4], b0[4], a1[4], b1[4];
#pragma unroll
        for (int mf = 0; mf < 4; ++mf)
            a0[mf] = *reinterpret_cast<const bf16x8*>(&Ab[(wr * 64 + mf * 16 + l15) * 64 + kb * 8]);
#pragma unroll
        for (int nf = 0; nf < 4; ++nf)
            b0[nf] = *reinterpret_cast<const bf16x8*>(&Bb[(wc * 64 + nf * 16 + l15) * 64 + kb * 8]);
        __builtin_amdgcn_sched_barrier(0);
#pragma unroll
        for (int mf = 0; mf < 4; ++mf)
            a1[mf] = *reinterpret_cast<const bf16x8*>(&Ab[(wr * 64 + mf * 16 + l15) * 64 + 32 + kb * 8]);
#pragma unroll
        for (int nf = 0; nf < 4; ++nf)
            b1[nf] = *reinterpret_cast<const bf16x8*>(&Bb[(wc * 64 + nf * 16 + l15) * 64 + 32 + kb * 8]);
        __builtin_amdgcn_sched_barrier(0);
        asm volatile("s_waitcnt lgkmcnt(8)" ::: "memory");
        __builtin_amdgcn_sched_barrier(0);
#pragma unroll
        for (int mf = 0; mf < 4; ++mf)
#pragma unroll
            for (int nf = 0; nf < 4; ++nf)
                acc[mf][nf] = __builtin_amdgcn_mfma_f32_16x16x32_bf16(a0[mf], b0[nf], acc[mf][nf], 0, 0, 0);
        asm volatile("s_waitcnt lgkmcnt(0)" ::: "memory");
        __builtin_amdgcn_sched_barrier(0);
#pragma unroll
        for (int mf = 0; mf < 4; ++mf)
#pragma unroll
            for (int nf = 0; nf < 4; ++nf)
                acc[mf][nf] = __builtin_amdgcn_mfma_f32_16x16x32_bf16(a1[mf], b1[nf], acc[mf][nf], 0, 0, 0);
        __builtin_amdgcn_sched_barrier(0);
        __builtin_amdgcn_s_barrier();
        if (t + 2 < NT) STAGE_G(t + 2, t & 1);
    }
#undef STAGE_G

#pragma unroll
    for (int mf = 0; mf < 4; ++mf)
#pragma unroll
        for (int nf = 0; nf < 4; ++nf)
#pragma unroll
            for (int r = 0; r < 4; ++r)
                C[(size_t)(m0 + wr * 64 + mf * 16 + kb * 4 + r) * N + n0 + wc * 64 + nf * 16 + l15] =
                    acc[mf][nf][r];
}

// ---------------------------------------------------------------------------
// gla_chunk (MFMA, fused u_pass): unchanged from R19 (passing).
// ---------------------------------------------------------------------------
__global__ __launch_bounds__(256) void gla_chunk(const __hip_bfloat16* __restrict__ qb,
                                                 const __hip_bfloat16* __restrict__ kb,
                                                 const __hip_bfloat16* __restrict__ vT,
                                                 const float* __restrict__ g,
                                                 __hip_bfloat16* __restrict__ qg,
                                                 __hip_bfloat16* __restrict__ U,
                                                 __hip_bfloat16* __restrict__ o1,
                                                 float* __restrict__ dlast) {
    __shared__ __align__(16) short SM[53248];   // 104 KB
    short* qg_l = SM;            // [0,16384)
    short* kd_l = SM + 16384;    // [16384,32768)
    short* V_l  = SM;            // alias [0,32768): 512 rows x 64 shorts
    short* kg_l = SM + 32768;    // [32768,49152): 256 rows x 64 shorts
    short* Am_l = SM + 49152;    // [49152,53248): 64x64

    const int chunk = blockIdx.x, bh = blockIdx.y;
    const int b = bh >> 2, h = bh & 3;
    const int t0 = b * 2048 + chunk * 64;
    const int tt0 = chunk * 64;
    const int tid = threadIdx.x;
    const float scale = 0.0625f;

    // ---- stage 1: thread = d column ----
    {
        const int d = tid;
        const float* gcol = g + (size_t)t0 * DKC + h * HDK_ + d;
        const __hip_bfloat16* qcol = qb + (size_t)t0 * DKC + h * HDK_ + d;
        const __hip_bfloat16* kcol = kb + (size_t)t0 * DKC + h * HDK_ + d;
        float run = 0.f;
#pragma unroll
        for (int i = 0; i < 64; ++i) run += gcol[(size_t)i * DKC];
        const float ebl = expf(run);
        dlast[((size_t)bh * NCH + chunk) * HDK_ + d] = ebl;

        bf16x8 kreg[8];
        run = 0.f;
#pragma unroll
        for (int i = 0; i < 64; ++i) {
            run += gcol[(size_t)i * DKC];
            float eb = expf(run);
            float qv = __bfloat162float(qcol[(size_t)i * DKC]) * eb * scale;
            float kdv = __bfloat162float(kcol[(size_t)i * DKC]) * expf(-run);
            qg[(size_t)(t0 + i) * DKC + h * HDK_ + d] = __float2bfloat16(qv);
            int bq = ((i * 512 + d * 2) ^ ((i & 7) << 4)) >> 1;
            qg_l[bq] = f2bf_bits(qv);
            kd_l[bq] = f2bf_bits(kdv);
            kreg[i >> 3][i & 7] = f2bf_bits(kdv * ebl);   // kg = kd * exp(b_last)
        }
#pragma unroll
        for (int j = 0; j < 8; ++j)
            *reinterpret_cast<bf16x8*>(&kg_l[d * 64 + ((j ^ (d & 7)) * 8)]) = kreg[j];
    }
    __syncthreads();

    const int wv = tid >> 6, lane = tid & 63;
    const int l15 = lane & 15, kb_ = lane >> 4;

    // ---- stage 2: A = tril(qg @ kd^T) ----
    {
        f32x4 accA[4];
#pragma unroll
        for (int sf = 0; sf < 4; ++sf) accA[sf] = (f32x4){0.f, 0.f, 0.f, 0.f};
        const int trow = wv * 16 + l15;
#pragma unroll
        for (int ks = 0; ks < 8; ++ks) {
            bf16x8 af = *reinterpret_cast<const bf16x8*>(
                &qg_l[((trow * 512 + (ks * 32 + kb_ * 8) * 2) ^ ((trow & 7) << 4)) >> 1]);
#pragma unroll
            for (int sf = 0; sf < 4; ++sf) {
                int srow = sf * 16 + l15;
                bf16x8 bfr = *reinterpret_cast<const bf16x8*>(
                    &kd_l[((srow * 512 + (ks * 32 + kb_ * 8) * 2) ^ ((srow & 7) << 4)) >> 1]);
                accA[sf] = __builtin_amdgcn_mfma_f32_16x16x32_bf16(af, bfr, accA[sf], 0, 0, 0);
            }
        }
#pragma unroll
        for (int sf = 0; sf < 4; ++sf)
#pragma unroll
            for (int r = 0; r < 4; ++r) {
                int t = wv * 16 + kb_ * 4 + r, s = sf * 16 + l15;
                float val = (t >= s) ? accA[sf][r] : 0.f;
                Am_l[((t * 128 + s * 2) ^ ((t & 7) << 4)) >> 1] = f2bf_bits(val);
            }
    }
    __syncthreads();

    // ---- stage 3: stage V (overwrites qg/kd), then o1 = Am @ vT^T ----
    {
        const int lr8 = lane >> 3, slot = lane & 7;
#pragma unroll
        for (int i8 = 0; i8 < 16; ++i8) {
            int vrow0 = wv * 128 + i8 * 8;
            const __hip_bfloat16* src =
                &vT[((size_t)bh * 512 + vrow0 + lr8) * 2048 + tt0 + (slot ^ (lr8 & 7)) * 8];
            gl_lds16(src, &V_l[vrow0 * 64]);
        }
    }
    __syncthreads();

    {
        f32x4 accO[4][8];
#pragma unroll
        for (int tf = 0; tf < 4; ++tf)
#pragma unroll
            for (int vf = 0; vf < 8; ++vf) accO[tf][vf] = (f32x4){0.f, 0.f, 0.f, 0.f};
#pragma unroll
        for (int kk = 0; kk < 2; ++kk) {
            bf16x8 af[4];
#pragma unroll
            for (int tf = 0; tf < 4; ++tf) {
                int row = tf * 16 + l15;
                af[tf] = *reinterpret_cast<const bf16x8*>(
                    &Am_l[((row * 128 + (kk * 32 + kb_ * 8) * 2) ^ ((row & 7) << 4)) >> 1]);
            }
#pragma unroll
            for (int vf = 0; vf < 8; ++vf) {
                int rv = wv * 128 + vf * 16 + l15;
                bf16x8 bfr = *reinterpret_cast<const bf16x8*>(
                    &V_l[((rv * 128 + (kk * 32 + kb_ * 8) * 2) ^ ((rv & 7) << 4)) >> 1]);
#pragma unroll
                for (int tf = 0; tf < 4; ++tf)
                    accO[tf][vf] = __builtin_amdgcn_mfma_f32_16x16x32_bf16(af[tf], bfr, accO[tf][vf], 0, 0, 0);
            }
        }
#pragma unroll
        for (int tf = 0; tf < 4; ++tf)
#pragma unroll
            for (int vf = 0; vf < 8; ++vf)
#pragma unroll
                for (int r = 0; r < 4; ++r) {
                    int t = tf * 16 + kb_ * 4 + r;
                    int vv = wv * 128 + vf * 16 + l15;
                    o1[(size_t)(t0 + t) * DVC + h * HDV_ + vv] = __float2bfloat16(accO[tf][vf][r]);
                }
    }

    // ---- stage 4 (fused u_pass): U[vc][d] = sum_t V[vc][t] * kg[d][t] ----
    {
        const size_t Ub = ((size_t)bh * NCH + chunk) * 131072;
        for (int d0 = 0; d0 < 256; d0 += 64) {
            f32x4 accU[8][4];
#pragma unroll
            for (int vf = 0; vf < 8; ++vf)
#pragma unroll
                for (int nf = 0; nf < 4; ++nf) accU[vf][nf] = (f32x4){0.f, 0.f, 0.f, 0.f};
#pragma unroll
            for (int kk = 0; kk < 2; ++kk) {
                bf16x8 av[8], bv[4];
#pragma unroll
                for (int vf = 0; vf < 8; ++vf) {
                    int rv = wv * 128 + vf * 16 + l15;
                    av[vf] = *reinterpret_cast<const bf16x8*>(
                        &V_l[((rv * 128 + (kk * 32 + kb_ * 8) * 2) ^ ((rv & 7) << 4)) >> 1]);
                }
#pragma unroll
                for (int nf = 0; nf < 4; ++nf) {
                    int row = d0 + nf * 16 + l15;
                    bv[nf] = *reinterpret_cast<const bf16x8*>(
                        &kg_l[row * 64 + (((kk * 4 + kb_) ^ (row & 7)) * 8)]);
                }
#pragma unroll
                for (int vf = 0; vf < 8; ++vf)
#pragma unroll
                    for (int nf = 0; nf < 4; ++nf)
                        accU[vf][nf] = __builtin_amdgcn_mfma_f32_16x16x32_bf16(av[vf], bv[nf], accU[vf][nf], 0, 0, 0);
            }
#pragma unroll
            for (int vf = 0; vf < 8; ++vf)
#pragma unroll
                for (int nf = 0; nf < 4; ++nf)
#pragma unroll
                    for (int r = 0; r < 4; ++r) {
                        int vc = wv * 128 + vf * 16 + kb_ * 4 + r;
                        int d = d0 + nf * 16 + l15;
                        U[Ub + (size_t)vc * 256 + d] = __float2bfloat16(accU[vf][nf][r]);
                    }
        }
    }
}

// ---------------------------------------------------------------------------
// scan_pass on U'[bh][c][vc][d]: exclusive scan over chunks, decay e(d)
// ---------------------------------------------------------------------------
__global__ __launch_bounds__(256) void scan_pass(__hip_bfloat16* __restrict__ U,
                                                 const float* __restrict__ dlast) {
    int gid = blockIdx.x * 256 + threadIdx.x;   // 131072
    int bh = gid >> 14;
    int rem = gid & 16383;
    int vc = rem >> 5;
    int dg = rem & 31;
    float S[8];
#pragma unroll
    for (int j = 0; j < 8; ++j) S[j] = 0.f;
    size_t base = (size_t)bh * NCH * 131072 + (size_t)vc * 256 + dg * 8;
    for (int c = 0; c < NCH; ++c) {
        __hip_bfloat16* p = U + base + (size_t)c * 131072;
        bf16x8 u = *reinterpret_cast<bf16x8*>(p);
        const float* dl = &dlast[((size_t)bh * NCH + c) * HDK_ + dg * 8];
        float4 e0 = *reinterpret_cast<const float4*>(dl);
        float4 e1 = *reinterpret_cast<const float4*>(dl + 4);
        float e[8] = {e0.x, e0.y, e0.z, e0.w, e1.x, e1.y, e1.z, e1.w};
        bf16x8 outv;
#pragma unroll
        for (int j = 0; j < 8; ++j) {
            outv[j] = f2bf_bits(S[j]);
            S[j] = S[j] * e[j] + bf2f(u[j]);
        }
        *reinterpret_cast<bf16x8*>(p) = outv;
    }
}

// ---------------------------------------------------------------------------
// o_gate (fused o_pass + rms_gate): per block (c, bh) computes ALL 512 v-cols
// of 64 tokens: o2 = o1 + qg@S' (4 vt quarters, parked bf16 in LDS), then
// in-block RMSNorm over 512 + silu(xg) gate -> gated (bf16).
// LDS: Av 16K + Bv 8K + oT 64x520 bf16 (66.6K) + red 1K = ~92 KB.
// ---------------------------------------------------------------------------
__global__ __launch_bounds__(256) void o_gate(const __hip_bfloat16* __restrict__ qg,
                                              const __hip_bfloat16* __restrict__ U,
                                              const __hip_bfloat16* __restrict__ o1,
                                              const __hip_bfloat16* __restrict__ xg,
                                              const float* __restrict__ rms_w,
                                              __hip_bfloat16* __restrict__ gated) {
    __shared__ __align__(16) short Av[128 * 64];    // 16 KB
    __shared__ __align__(16) short Bv[64 * 64];     // 8 KB
    __shared__ __align__(16) short oT[64 * 520];    // 66.6 KB  [t][vc], pad 8
    __shared__ float red[64][4];
    const int c = blockIdx.x, bh = blockIdx.y;
    const int b = bh >> 2, h = bh & 3;
    const int t0 = b * 2048 + c * 64;
    const int tid = threadIdx.x;
    const int wave = tid >> 6, lane = tid & 63;
    const int wr = wave >> 1, wc = wave & 1;
    const int l15 = lane & 15, kb = lane >> 4;
    const int lr8 = lane >> 3, lc8 = (lane & 7) * 8;
    const size_t Ub = ((size_t)bh * NCH + c) * 131072;

    for (int vt = 0; vt < 4; ++vt) {
        const int vc0 = vt * 128;
        f32x4 acc[4][2];
#pragma unroll
        for (int mf = 0; mf < 4; ++mf)
#pragma unroll
            for (int nf = 0; nf < 2; ++nf) acc[mf][nf] = (f32x4){0.f, 0.f, 0.f, 0.f};

        for (int ks = 0; ks < 4; ++ks) {
            const int d0 = ks * 64;
#pragma unroll
            for (int j = 0; j < 4; ++j) {
                int inst = wave * 4 + j;
                int r = inst * 8 + lr8;
                gl_lds16(&U[Ub + (size_t)(vc0 + r) * 256 + d0 + lc8], &Av[inst * 512]);
            }
#pragma unroll
            for (int j = 0; j < 2; ++j) {
                int inst = wave * 2 + j;
                int r = inst * 8 + lr8;
                gl_lds16(&qg[(size_t)(t0 + r) * DKC + h * HDK_ + d0 + lc8], &Bv[inst * 512]);
            }
            __syncthreads();
#pragma unroll
            for (int kk = 0; kk < 2; ++kk) {
                bf16x8 af[4], bfr[2];
#pragma unroll
                for (int mf = 0; mf < 4; ++mf)
                    af[mf] = *reinterpret_cast<const bf16x8*>(&Av[(wr * 64 + mf * 16 + l15) * 64 + kk * 32 + kb * 8]);
#pragma unroll
                for (int nf = 0; nf < 2; ++nf)
                    bfr[nf] = *reinterpret_cast<const bf16x8*>(&Bv[(wc * 32 + nf * 16 + l15) * 64 + kk * 32 + kb * 8]);
#pragma unroll
                for (int mf = 0; mf < 4; ++mf)
#pragma unroll
                    for (int nf = 0; nf < 2; ++nf)
                        acc[mf][nf] = __builtin_amdgcn_mfma_f32_16x16x32_bf16(af[mf], bfr[nf], acc[mf][nf], 0, 0, 0);
            }
            __syncthreads();
        }
        // park quarter: oT[t][vc0+vc] bf16 (inter-term only)
#pragma unroll
        for (int mf = 0; mf < 4; ++mf)
#pragma unroll
            for (int nf = 0; nf < 2; ++nf)
#pragma unroll
                for (int r = 0; r < 4; ++r)
                    oT[(wc * 32 + nf * 16 + l15) * 520 + vc0 + wr * 64 + mf * 16 + kb * 4 + r] =
                        f2bf_bits(acc[mf][nf][r]);
        // no barrier needed here: next ks staging writes Av/Bv (disjoint from oT);
        // __syncthreads inside next vt's ks loop orders everything. But oT reads
        // happen after the vt loop's final barrier below.
    }
    __syncthreads();

    // pass A: o2 = bf16(oT + o1); row sums of squares
    {
        const int row = tid >> 2, q = tid & 3;
        float s = 0.f;
        const size_t gbase = (size_t)(t0 + row) * DVC + h * HDV_ + q * 128;
#pragma unroll
        for (int j = 0; j < 16; ++j) {
            bf16x8 ov = *reinterpret_cast<const bf16x8*>(&oT[row * 520 + q * 128 + j * 8]);
            bf16x8 o1v = *reinterpret_cast<const bf16x8*>(&o1[gbase + j * 8]);
            bf16x8 o2v;
#pragma unroll
            for (int e = 0; e < 8; ++e) {
                float v = bf2f(ov[e]) + bf2f(o1v[e]);
                short sb = f2bf_bits(v);
                o2v[e] = sb;
                float vb = bf2f(sb);
                s += vb * vb;
            }
            *reinterpret_cast<bf16x8*>(&oT[row * 520 + q * 128 + j * 8]) = o2v;
        }
        red[row][q] = s;
    }
    __syncthreads();

    // pass B: gated = o2 * rms * w * silu(xg), coalesced
#pragma unroll
    for (int it = 0; it < 16; ++it) {
        int idx = tid + it * 256;        // 0..4095
        int row = idx >> 6;              // 0..63
        int col8 = (idx & 63) * 8;       // 0..504
        float tot = red[row][0] + red[row][1] + red[row][2] + red[row][3];
        float rms = rsqrtf(tot * (1.f / 512.f) + 1e-5f);
        bf16x8 o2v = *reinterpret_cast<const bf16x8*>(&oT[row * 520 + col8]);
        const size_t gbase = (size_t)(t0 + row) * DVC + h * HDV_ + col8;
        bf16x8 xgv = *reinterpret_cast<const bf16x8*>(&xg[gbase]);
        float4 w0 = *reinterpret_cast<const float4*>(&rms_w[col8]);
        float4 w1 = *reinterpret_cast<const float4*>(&rms_w[col8 + 4]);
        float wv[8] = {w0.x, w0.y, w0.z, w0.w, w1.x, w1.y, w1.z, w1.w};
        bf16x8 outv;
#pragma unroll
        for (int e = 0; e < 8; ++e) {
            float gv = bf2f(xgv[e]);
            float sg = gv / (1.f + expf(-gv));
            outv[e] = f2bf_bits(bf2f(o2v[e]) * rms * wv[e] * sg);
        }
        *reinterpret_cast<bf16x8*>((short*)gated + gbase) = outv;
    }
}

// ---------------------------------------------------------------------------
extern "C" void kernel_launch(void* const* d_in, const int* in_sizes, int n_in,
                              void* d_out, int out_size, void* d_ws, size_t ws_size,
                              hipStream_t stream) {
    const float* x    = (const float*)d_in[0];
    const float* Wq   = (const float*)d_in[1];
    const float* Wk   = (const float*)d_in[2];
    const float* Wv   = (const float*)d_in[3];
    const float* Wg   = (const float*)d_in[4];
    const float* Wgk1 = (const float*)d_in[5];
    const float* Wgk2 = (const float*)d_in[6];
    const float* bgk2 = (const float*)d_in[7];
    const float* Wo   = (const float*)d_in[8];
    const float* rmsw = (const float*)d_in[9];
    float* out = (float*)d_out;
    float* ws = (float*)d_ws;

    const size_t M1 = 1ull << 20;   // floats
    __hip_bfloat16* xb    = (__hip_bfloat16*)ws;              // [0,2M)   8 MB
    __hip_bfloat16* WtAll = (__hip_bfloat16*)(ws + 2 * M1);   // [2M,5M)  12 MB
    __hip_bfloat16* q_b   = (__hip_bfloat16*)(ws + 5 * M1);   // [5M,7M)  8 MB
    __hip_bfloat16* k_b   = (__hip_bfloat16*)(ws + 7 * M1);   // [7M,9M)  8 MB
    float*          g     = ws + 13 * M1;                     // [13M,17M) 16 MB
    __hip_bfloat16* U     = (__hip_bfloat16*)ws;              // [0,16M) 64 MB overlay
    __hip_bfloat16* xg_b  = (__hip_bfloat16*)(ws + 17 * M1);  // [17M,21M) 16 MB
    __hip_bfloat16* qgb   = (__hip_bfloat16*)(ws + 21 * M1);  // [21M,23M) 8 MB
    __hip_bfloat16* vT    = (__hip_bfloat16*)(ws + 25 * M1);  // [25M,29M) 16 MB
    __hip_bfloat16* o1    = (__hip_bfloat16*)(ws + 29 * M1);  // [29M,33M) 16 MB
    float*          dlast = ws + 37 * M1 + 65536;             // 256 KB
    __hip_bfloat16* WtO   = (__hip_bfloat16*)(ws + 38 * M1);  // [38M,39M) 4 MB
    __hip_bfloat16* gated = (__hip_bfloat16*)(ws + 25 * M1);  // over vT (dead after gla_chunk)

    prep_all<<<12288, 256, 0, stream>>>(Wq, Wk, Wv, Wg, Wo, WtAll, WtO,
                                        x, Wgk1, Wgk2, bgk2, xb, g);

    gemm256<<<dim3(24, 32), 512, 0, stream>>>(xb, WtAll, q_b, k_b, vT, xg_b);

    gla_chunk<<<dim3(NCH, 8), 256, 0, stream>>>(q_b, k_b, vT, g, qgb, U, o1, dlast);

    scan_pass<<<512, 256, 0, stream>>>(U, dlast);
    o_gate<<<dim3(NCH, 8), 256, 0, stream>>>(qgb, U, o1, xg_b, rmsw, gated);

    gemm_bf16<<<dim3(8, 32), 256, 0, stream>>>(gated, WtO, out, TOK, DM, DVC);
}

// Round 22
// 224.440 us; speedup vs baseline: 1.0062x; 1.0062x over previous
//
#include <hip/hip_runtime.h>
#include <hip/hip_bf16.h>
#include <math.h>

#define TOK  4096
#define DM   1024
#define DKC  1024
#define DVC  2048
#define NH   4
#define HDK_ 256
#define HDV_ 512
#define NCH  32
#define CHK  64

typedef __attribute__((ext_vector_type(8))) short bf16x8;
typedef __attribute__((ext_vector_type(4))) float f32x4;

__device__ inline float bf2f(short s) {
    unsigned int b = ((unsigned int)(unsigned short)s) << 16;
    return __uint_as_float(b);
}
__device__ inline short f2bf_bits(float f) {
    __hip_bfloat16 h = __float2bfloat16(f);
    return *reinterpret_cast<short*>(&h);
}

// async global->LDS, 16B per lane; lds dest = base + lane*16 (wave-uniform base)
__device__ __forceinline__ void gl_lds16(const void* g, void* l) {
    __builtin_amdgcn_global_load_lds((const __attribute__((address_space(1))) void*)g,
                                     (__attribute__((address_space(3))) void*)l, 16, 0, 0);
}

// ---------------------------------------------------------------------------
// prep_all: fused weight transposes (bid<8192) + x-path (bid>=8192).
// ---------------------------------------------------------------------------
__global__ __launch_bounds__(256) void prep_all(const float* __restrict__ Wq,
                                                const float* __restrict__ Wk,
                                                const float* __restrict__ Wv,
                                                const float* __restrict__ Wg,
                                                const float* __restrict__ Wo,
                                                __hip_bfloat16* __restrict__ WtAll,
                                                __hip_bfloat16* __restrict__ WtO,
                                                const float* __restrict__ x,
                                                const float* __restrict__ W1,
                                                const float* __restrict__ W2,
                                                const float* __restrict__ b2,
                                                __hip_bfloat16* __restrict__ xb,
                                                float* __restrict__ g) {
    const int bid = blockIdx.x;
    const int tid = threadIdx.x;
    if (bid < 8192) {
        __shared__ float tile[32][33];
        const float* W; __hip_bfloat16* Wt; int K, N, r;
        if (bid < 1024)      { W = Wq; Wt = WtAll;               K = 1024; N = 1024; r = bid; }
        else if (bid < 2048) { W = Wk; Wt = WtAll + 1024 * 1024; K = 1024; N = 1024; r = bid - 1024; }
        else if (bid < 4096) { W = Wv; Wt = WtAll + 2048 * 1024; K = 1024; N = 2048; r = bid - 2048; }
        else if (bid < 6144) { W = Wg; Wt = WtAll + 4096 * 1024; K = 1024; N = 2048; r = bid - 4096; }
        else                 { W = Wo; Wt = WtO;                 K = 2048; N = 1024; r = bid - 6144; }
        const int ncols = N >> 5;
        const int n0 = (r % ncols) * 32, k0 = (r / ncols) * 32;
        const int tx = tid & 31, ty = tid >> 5;
#pragma unroll
        for (int i = 0; i < 32; i += 8)
            tile[ty + i][tx] = W[(size_t)(k0 + ty + i) * N + n0 + tx];
        __syncthreads();
#pragma unroll
        for (int i = 0; i < 32; i += 8)
            Wt[(size_t)(n0 + ty + i) * K + k0 + tx] = __float2bfloat16(tile[tx][ty + i]);
    } else {
        __shared__ float xl[1024];
        __shared__ float red[16][17];
        __shared__ float t1l[16];
        const int t = bid - 8192;
        float4 xv = *reinterpret_cast<const float4*>(&x[(size_t)t * DM + tid * 4]);
        *reinterpret_cast<float4*>(&xl[tid * 4]) = xv;
        short4 xs;
        xs.x = f2bf_bits(xv.x); xs.y = f2bf_bits(xv.y);
        xs.z = f2bf_bits(xv.z); xs.w = f2bf_bits(xv.w);
        *reinterpret_cast<short4*>((short*)xb + (size_t)t * DM + tid * 4) = xs;
        __syncthreads();
        const int o = tid & 15, p = tid >> 4;
        float s = 0.f;
#pragma unroll 8
        for (int m = 0; m < 64; ++m) {
            int kk = p * 64 + m;
            s += xl[kk] * W1[kk * 16 + o];
        }
        red[p][o] = s;
        __syncthreads();
        if (tid < 16) {
            float tot = 0.f;
#pragma unroll
            for (int pp = 0; pp < 16; ++pp) tot += red[pp][tid];
            t1l[tid] = tot;
        }
        __syncthreads();
#pragma unroll
        for (int j = 0; j < 4; ++j) {
            int c = tid + j * 256;
            float acc = b2[c];
#pragma unroll
            for (int r2 = 0; r2 < 16; ++r2) acc += t1l[r2] * W2[r2 * 1024 + c];
            float ls = fminf(acc, 0.f) - log1pf(expf(-fabsf(acc)));
            g[(size_t)t * DKC + c] = ls * (1.f / 16.f);
        }
    }
}

// ---------------------------------------------------------------------------
// FUSED projection GEMM, 128x256 tile, 512 thr (8 waves 2Mx4N), BK=64.
// (converged schedule — do not modify)
// ---------------------------------------------------------------------------
__global__ __launch_bounds__(512) void gemm256(const __hip_bfloat16* __restrict__ A,
                                               const __hip_bfloat16* __restrict__ Wt,
                                               __hip_bfloat16* __restrict__ qo,
                                               __hip_bfloat16* __restrict__ ko,
                                               __hip_bfloat16* __restrict__ vT,
                                               __hip_bfloat16* __restrict__ xgo) {
    __shared__ __align__(16) short SM[9 * 8192];   // 144 KB ring
    const int K = 1024, NT = 16;
    const int tid = threadIdx.x;
    const int wave = tid >> 6, lane = tid & 63;
    const int wr = wave >> 2;        // M half (0..1)
    const int wc = wave & 3;         // N quarter (0..3)
    const int hc = wc >> 1;          // B unit (lo/hi 128)
    const int l15 = lane & 15, kb = lane >> 4;
    const int m0 = blockIdx.y * 128, n0 = blockIdx.x * 256;

    const bool isV = (n0 >= 2048 && n0 < 4096);
    __hip_bfloat16* dst = nullptr; int ldd = 0, nloc0 = 0;
    if (n0 < 1024)       { dst = qo;  ldd = 1024; nloc0 = n0; }
    else if (n0 < 2048)  { dst = ko;  ldd = 1024; nloc0 = n0 - 1024; }
    else if (n0 >= 4096) { dst = xgo; ldd = 2048; nloc0 = n0 - 4096; }

    f32x4 acc[4][4];
#pragma unroll
    for (int mf = 0; mf < 4; ++mf)
#pragma unroll
        for (int nf = 0; nf < 4; ++nf) acc[mf][nf] = (f32x4){0.f, 0.f, 0.f, 0.f};

    auto stage_unit = [&](int u) {
        int tk = u / 3, p = u % 3;
        int slot = u % 9;
#pragma unroll
        for (int j = 0; j < 2; ++j) {
            int row = (wave * 2 + j) * 8 + (lane >> 3);   // 0..127
            int srcg = (lane & 7) ^ (row & 7);
            const __hip_bfloat16* src =
                (p == 0) ? &A[(size_t)(m0 + row) * K + tk * 64 + srcg * 8]
                         : &Wt[(size_t)(n0 + (p - 1) * 128 + row) * K + tk * 64 + srcg * 8];
            gl_lds16(src, &SM[slot * 8192 + (wave * 2 + j) * 512]);
        }
    };

    for (int u = 0; u <= 5; ++u) stage_unit(u);

    const int ULAST = 3 * NT - 1;
    for (int t = 0; t < NT; ++t) {
        if (t < NT - 1) asm volatile("s_waitcnt vmcnt(6)" ::: "memory");
        else            asm volatile("s_waitcnt vmcnt(0)" ::: "memory");
        __builtin_amdgcn_sched_barrier(0);
        __builtin_amdgcn_s_barrier();

        if (3 * t + 6 <= ULAST) stage_unit(3 * t + 6);
        if (3 * t + 7 <= ULAST) stage_unit(3 * t + 7);
        if (3 * t + 8 <= ULAST) stage_unit(3 * t + 8);
        __builtin_amdgcn_sched_barrier(0);

        const short* Abase = &SM[((3 * t) % 9) * 8192];
        const short* Bbase = &SM[((3 * t + 1 + hc) % 9) * 8192];

        bf16x8 a0[4], b0[4], a1[4], b1[4];
#pragma unroll
        for (int mf = 0; mf < 4; ++mf) {
            int row = wr * 64 + mf * 16 + l15;
            a0[mf] = *reinterpret_cast<const bf16x8*>(&Abase[row * 64 + (kb ^ (row & 7)) * 8]);
        }
#pragma unroll
        for (int nf = 0; nf < 4; ++nf) {
            int row = (wc & 1) * 64 + nf * 16 + l15;
            b0[nf] = *reinterpret_cast<const bf16x8*>(&Bbase[row * 64 + (kb ^ (row & 7)) * 8]);
        }
        __builtin_amdgcn_sched_barrier(0);
#pragma unroll
        for (int mf = 0; mf < 4; ++mf) {
            int row = wr * 64 + mf * 16 + l15;
            a1[mf] = *reinterpret_cast<const bf16x8*>(&Abase[row * 64 + ((4 + kb) ^ (row & 7)) * 8]);
        }
#pragma unroll
        for (int nf = 0; nf < 4; ++nf) {
            int row = (wc & 1) * 64 + nf * 16 + l15;
            b1[nf] = *reinterpret_cast<const bf16x8*>(&Bbase[row * 64 + ((4 + kb) ^ (row & 7)) * 8]);
        }
        __builtin_amdgcn_sched_barrier(0);
        asm volatile("s_waitcnt lgkmcnt(8)" ::: "memory");
        __builtin_amdgcn_sched_barrier(0);
        __builtin_amdgcn_s_setprio(1);
#pragma unroll
        for (int mf = 0; mf < 4; ++mf)
#pragma unroll
            for (int nf = 0; nf < 4; ++nf)
                acc[mf][nf] = __builtin_amdgcn_mfma_f32_16x16x32_bf16(a0[mf], b0[nf], acc[mf][nf], 0, 0, 0);
        __builtin_amdgcn_s_setprio(0);
        asm volatile("s_waitcnt lgkmcnt(0)" ::: "memory");
        __builtin_amdgcn_sched_barrier(0);
        __builtin_amdgcn_s_setprio(1);
#pragma unroll
        for (int mf = 0; mf < 4; ++mf)
#pragma unroll
            for (int nf = 0; nf < 4; ++nf)
                acc[mf][nf] = __builtin_amdgcn_mfma_f32_16x16x32_bf16(a1[mf], b1[nf], acc[mf][nf], 0, 0, 0);
        __builtin_amdgcn_s_setprio(0);
    }

    if (!isV) {
#pragma unroll
        for (int mf = 0; mf < 4; ++mf)
#pragma unroll
            for (int nf = 0; nf < 4; ++nf)
#pragma unroll
                for (int r = 0; r < 4; ++r)
                    dst[(size_t)(m0 + wr * 64 + mf * 16 + kb * 4 + r) * ldd +
                        nloc0 + wc * 64 + nf * 16 + l15] = __float2bfloat16(acc[mf][nf][r]);
    } else {
        __syncthreads();
        short* Cl = SM;                  // [256 vc][132] shorts
#pragma unroll
        for (int mf = 0; mf < 4; ++mf)
#pragma unroll
            for (int nf = 0; nf < 4; ++nf)
#pragma unroll
                for (int r = 0; r < 4; ++r) {
                    int trow = wr * 64 + mf * 16 + kb * 4 + r;      // 0..127
                    int vcol = wc * 64 + nf * 16 + l15;             // 0..255
                    Cl[vcol * 132 + trow] = f2bf_bits(acc[mf][nf][r]);
                }
        __syncthreads();
        const int vcg0 = n0 - 2048;
        const int bh = (m0 >> 11) * NH + (vcg0 >> 9);
        const int vl0 = vcg0 & 511;
        const int tl0 = m0 & 2047;
        short* vTs = (short*)vT;
#pragma unroll
        for (int it = 0; it < 8; ++it) {
            int idx = tid + it * 512;    // 0..4095
            int row = idx >> 4;          // 0..255
            int c8 = (idx & 15) * 8;     // 0..120
            bf16x8 vv = *reinterpret_cast<const bf16x8*>(&Cl[row * 132 + c8]);
            *reinterpret_cast<bf16x8*>(
                &vTs[((size_t)(bh * 512 + vl0 + row)) * 2048 + tl0 + c8]) = vv;
        }
    }
}

// ---------------------------------------------------------------------------
// Double-buffered bf16 MFMA GEMM, f32 C (final Wo projection).
// ---------------------------------------------------------------------------
__global__ __launch_bounds__(256) void gemm_bf16(const __hip_bfloat16* __restrict__ A,
                                                 const __hip_bfloat16* __restrict__ Wt,
                                                 float* __restrict__ C,
                                                 int M, int N, int K) {
    __shared__ __align__(16) short Buf[2][2][128 * 64];   // [dbuf][A/B] 64 KB
    const int tid = threadIdx.x;
    const int wave = tid >> 6, lane = tid & 63;
    const int wr = wave >> 1, wc = wave & 1;
    const int m0 = blockIdx.y * 128, n0 = blockIdx.x * 128;
    const int l15 = lane & 15, kb = lane >> 4;
    const int lr8 = lane >> 3, lc8 = (lane & 7) * 8;
    const int NT = K >> 6;

    f32x4 acc[4][4];
#pragma unroll
    for (int mf = 0; mf < 4; ++mf)
#pragma unroll
        for (int nf = 0; nf < 4; ++nf) acc[mf][nf] = (f32x4){0.f, 0.f, 0.f, 0.f};

#define STAGE_G(kt, bi)                                                          \
    {                                                                            \
        int k0s = (kt) * 64;                                                     \
        _Pragma("unroll")                                                        \
        for (int j = 0; j < 4; ++j) {                                            \
            int inst = wave * 4 + j;                                             \
            int r = inst * 8 + lr8;                                              \
            gl_lds16(&A[(size_t)(m0 + r) * K + k0s + lc8], &Buf[bi][0][inst * 512]); \
            gl_lds16(&Wt[(size_t)(n0 + r) * K + k0s + lc8], &Buf[bi][1][inst * 512]); \
        }                                                                        \
    }

    STAGE_G(0, 0);
    STAGE_G(1, 1);

    for (int t = 0; t < NT; ++t) {
        if (t + 1 < NT) asm volatile("s_waitcnt vmcnt(8)" ::: "memory");
        else            asm volatile("s_waitcnt vmcnt(0)" ::: "memory");
        __builtin_amdgcn_sched_barrier(0);
        __builtin_amdgcn_s_barrier();
        const short* Ab = Buf[t & 1][0];
        const short* Bb = Buf[t & 1][1];
        bf16x8 a0[4], b0[4], a1[4], b1[4];
#pragma unroll
        for (int mf = 0; mf < 4; ++mf)
            a0[mf] = *reinterpret_cast<const bf16x8*>(&Ab[(wr * 64 + mf * 16 + l15) * 64 + kb * 8]);
#pragma unroll
        for (int nf = 0; nf < 4; ++nf)
            b0[nf] = *reinterpret_cast<const bf16x8*>(&Bb[(wc * 64 + nf * 16 + l15) * 64 + kb * 8]);
        __builtin_amdgcn_sched_barrier(0);
#pragma unroll
        for (int mf = 0; mf < 4; ++mf)
            a1[mf] = *reinterpret_cast<const bf16x8*>(&Ab[(wr * 64 + mf * 16 + l15) * 64 + 32 + kb * 8]);
#pragma unroll
        for (int nf = 0; nf < 4; ++nf)
            b1[nf] = *reinterpret_cast<const bf16x8*>(&Bb[(wc * 64 + nf * 16 + l15) * 64 + 32 + kb * 8]);
        __builtin_amdgcn_sched_barrier(0);
        asm volatile("s_waitcnt lgkmcnt(8)" ::: "memory");
        __builtin_amdgcn_sched_barrier(0);
#pragma unroll
        for (int mf = 0; mf < 4; ++mf)
#pragma unroll
            for (int nf = 0; nf < 4; ++nf)
                acc[mf][nf] = __builtin_amdgcn_mfma_f32_16x16x32_bf16(a0[mf], b0[nf], acc[mf][nf], 0, 0, 0);
        asm volatile("s_waitcnt lgkmcnt(0)" ::: "memory");
        __builtin_amdgcn_sched_barrier(0);
#pragma unroll
        for (int mf = 0; mf < 4; ++mf)
#pragma unroll
            for (int nf = 0; nf < 4; ++nf)
                acc[mf][nf] = __builtin_amdgcn_mfma_f32_16x16x32_bf16(a1[mf], b1[nf], acc[mf][nf], 0, 0, 0);
        __builtin_amdgcn_sched_barrier(0);
        __builtin_amdgcn_s_barrier();
        if (t + 2 < NT) STAGE_G(t + 2, t & 1);
    }
#undef STAGE_G

#pragma unroll
    for (int mf = 0; mf < 4; ++mf)
#pragma unroll
        for (int nf = 0; nf < 4; ++nf)
#pragma unroll
            for (int r = 0; r < 4; ++r)
                C[(size_t)(m0 + wr * 64 + mf * 16 + kb * 4 + r) * N + n0 + wc * 64 + nf * 16 + l15] =
                    acc[mf][nf][r];
}

// ---------------------------------------------------------------------------
// gla_chunk (MFMA, fused u_pass): stage-1 single-pass g (register-cached).
// ---------------------------------------------------------------------------
__global__ __launch_bounds__(256) void gla_chunk(const __hip_bfloat16* __restrict__ qb,
                                                 const __hip_bfloat16* __restrict__ kb,
                                                 const __hip_bfloat16* __restrict__ vT,
                                                 const float* __restrict__ g,
                                                 __hip_bfloat16* __restrict__ qg,
                                                 __hip_bfloat16* __restrict__ U,
                                                 __hip_bfloat16* __restrict__ o1,
                                                 float* __restrict__ dlast) {
    __shared__ __align__(16) short SM[53248];   // 104 KB
    short* qg_l = SM;            // [0,16384)
    short* kd_l = SM + 16384;    // [16384,32768)
    short* V_l  = SM;            // alias [0,32768): 512 rows x 64 shorts
    short* kg_l = SM + 32768;    // [32768,49152): 256 rows x 64 shorts
    short* Am_l = SM + 49152;    // [49152,53248): 64x64

    const int chunk = blockIdx.x, bh = blockIdx.y;
    const int b = bh >> 2, h = bh & 3;
    const int t0 = b * 2048 + chunk * 64;
    const int tt0 = chunk * 64;
    const int tid = threadIdx.x;
    const float scale = 0.0625f;

    // ---- stage 1: thread = d column; g read ONCE into registers ----
    {
        const int d = tid;
        const float* gcol = g + (size_t)t0 * DKC + h * HDK_ + d;
        const __hip_bfloat16* qcol = qb + (size_t)t0 * DKC + h * HDK_ + d;
        const __hip_bfloat16* kcol = kb + (size_t)t0 * DKC + h * HDK_ + d;
        float garr[64];
#pragma unroll
        for (int i = 0; i < 64; ++i) garr[i] = gcol[(size_t)i * DKC];
        float run = 0.f;
#pragma unroll
        for (int i = 0; i < 64; ++i) run += garr[i];
        const float ebl = expf(run);
        dlast[((size_t)bh * NCH + chunk) * HDK_ + d] = ebl;

        bf16x8 kreg[8];
        run = 0.f;
#pragma unroll
        for (int i = 0; i < 64; ++i) {
            run += garr[i];
            float eb = expf(run);
            float qv = __bfloat162float(qcol[(size_t)i * DKC]) * eb * scale;
            float kdv = __bfloat162float(kcol[(size_t)i * DKC]) * expf(-run);
            qg[(size_t)(t0 + i) * DKC + h * HDK_ + d] = __float2bfloat16(qv);
            int bq = ((i * 512 + d * 2) ^ ((i & 7) << 4)) >> 1;
            qg_l[bq] = f2bf_bits(qv);
            kd_l[bq] = f2bf_bits(kdv);
            kreg[i >> 3][i & 7] = f2bf_bits(kdv * ebl);   // kg = kd * exp(b_last)
        }
#pragma unroll
        for (int j = 0; j < 8; ++j)
            *reinterpret_cast<bf16x8*>(&kg_l[d * 64 + ((j ^ (d & 7)) * 8)]) = kreg[j];
    }
    __syncthreads();

    const int wv = tid >> 6, lane = tid & 63;
    const int l15 = lane & 15, kb_ = lane >> 4;

    // ---- stage 2: A = tril(qg @ kd^T) ----
    {
        f32x4 accA[4];
#pragma unroll
        for (int sf = 0; sf < 4; ++sf) accA[sf] = (f32x4){0.f, 0.f, 0.f, 0.f};
        const int trow = wv * 16 + l15;
#pragma unroll
        for (int ks = 0; ks < 8; ++ks) {
            bf16x8 af = *reinterpret_cast<const bf16x8*>(
                &qg_l[((trow * 512 + (ks * 32 + kb_ * 8) * 2) ^ ((trow & 7) << 4)) >> 1]);
#pragma unroll
            for (int sf = 0; sf < 4; ++sf) {
                int srow = sf * 16 + l15;
                bf16x8 bfr = *reinterpret_cast<const bf16x8*>(
                    &kd_l[((srow * 512 + (ks * 32 + kb_ * 8) * 2) ^ ((srow & 7) << 4)) >> 1]);
                accA[sf] = __builtin_amdgcn_mfma_f32_16x16x32_bf16(af, bfr, accA[sf], 0, 0, 0);
            }
        }
#pragma unroll
        for (int sf = 0; sf < 4; ++sf)
#pragma unroll
            for (int r = 0; r < 4; ++r) {
                int t = wv * 16 + kb_ * 4 + r, s = sf * 16 + l15;
                float val = (t >= s) ? accA[sf][r] : 0.f;
                Am_l[((t * 128 + s * 2) ^ ((t & 7) << 4)) >> 1] = f2bf_bits(val);
            }
    }
    __syncthreads();

    // ---- stage 3: stage V (overwrites qg/kd), then o1 = Am @ vT^T ----
    {
        const int lr8 = lane >> 3, slot = lane & 7;
#pragma unroll
        for (int i8 = 0; i8 < 16; ++i8) {
            int vrow0 = wv * 128 + i8 * 8;
            const __hip_bfloat16* src =
                &vT[((size_t)bh * 512 + vrow0 + lr8) * 2048 + tt0 + (slot ^ (lr8 & 7)) * 8];
            gl_lds16(src, &V_l[vrow0 * 64]);
        }
    }
    __syncthreads();

    {
        f32x4 accO[4][8];
#pragma unroll
        for (int tf = 0; tf < 4; ++tf)
#pragma unroll
            for (int vf = 0; vf < 8; ++vf) accO[tf][vf] = (f32x4){0.f, 0.f, 0.f, 0.f};
#pragma unroll
        for (int kk = 0; kk < 2; ++kk) {
            bf16x8 af[4];
#pragma unroll
            for (int tf = 0; tf < 4; ++tf) {
                int row = tf * 16 + l15;
                af[tf] = *reinterpret_cast<const bf16x8*>(
                    &Am_l[((row * 128 + (kk * 32 + kb_ * 8) * 2) ^ ((row & 7) << 4)) >> 1]);
            }
#pragma unroll
            for (int vf = 0; vf < 8; ++vf) {
                int rv = wv * 128 + vf * 16 + l15;
                bf16x8 bfr = *reinterpret_cast<const bf16x8*>(
                    &V_l[((rv * 128 + (kk * 32 + kb_ * 8) * 2) ^ ((rv & 7) << 4)) >> 1]);
#pragma unroll
                for (int tf = 0; tf < 4; ++tf)
                    accO[tf][vf] = __builtin_amdgcn_mfma_f32_16x16x32_bf16(af[tf], bfr, accO[tf][vf], 0, 0, 0);
            }
        }
#pragma unroll
        for (int tf = 0; tf < 4; ++tf)
#pragma unroll
            for (int vf = 0; vf < 8; ++vf)
#pragma unroll
                for (int r = 0; r < 4; ++r) {
                    int t = tf * 16 + kb_ * 4 + r;
                    int vv = wv * 128 + vf * 16 + l15;
                    o1[(size_t)(t0 + t) * DVC + h * HDV_ + vv] = __float2bfloat16(accO[tf][vf][r]);
                }
    }

    // ---- stage 4 (fused u_pass): U[vc][d] = sum_t V[vc][t] * kg[d][t] ----
    {
        const size_t Ub = ((size_t)bh * NCH + chunk) * 131072;
        for (int d0 = 0; d0 < 256; d0 += 64) {
            f32x4 accU[8][4];
#pragma unroll
            for (int vf = 0; vf < 8; ++vf)
#pragma unroll
                for (int nf = 0; nf < 4; ++nf) accU[vf][nf] = (f32x4){0.f, 0.f, 0.f, 0.f};
#pragma unroll
            for (int kk = 0; kk < 2; ++kk) {
                bf16x8 av[8], bv[4];
#pragma unroll
                for (int vf = 0; vf < 8; ++vf) {
                    int rv = wv * 128 + vf * 16 + l15;
                    av[vf] = *reinterpret_cast<const bf16x8*>(
                        &V_l[((rv * 128 + (kk * 32 + kb_ * 8) * 2) ^ ((rv & 7) << 4)) >> 1]);
                }
#pragma unroll
                for (int nf = 0; nf < 4; ++nf) {
                    int row = d0 + nf * 16 + l15;
                    bv[nf] = *reinterpret_cast<const bf16x8*>(
                        &kg_l[row * 64 + (((kk * 4 + kb_) ^ (row & 7)) * 8)]);
                }
#pragma unroll
                for (int vf = 0; vf < 8; ++vf)
#pragma unroll
                    for (int nf = 0; nf < 4; ++nf)
                        accU[vf][nf] = __builtin_amdgcn_mfma_f32_16x16x32_bf16(av[vf], bv[nf], accU[vf][nf], 0, 0, 0);
            }
#pragma unroll
            for (int vf = 0; vf < 8; ++vf)
#pragma unroll
                for (int nf = 0; nf < 4; ++nf)
#pragma unroll
                    for (int r = 0; r < 4; ++r) {
                        int vc = wv * 128 + vf * 16 + kb_ * 4 + r;
                        int d = d0 + nf * 16 + l15;
                        U[Ub + (size_t)vc * 256 + d] = __float2bfloat16(accU[vf][nf][r]);
                    }
        }
    }
}

// ---------------------------------------------------------------------------
// scan_pass on U'[bh][c][vc][d]: exclusive scan over chunks, decay e(d)
// ---------------------------------------------------------------------------
__global__ __launch_bounds__(256) void scan_pass(__hip_bfloat16* __restrict__ U,
                                                 const float* __restrict__ dlast) {
    int gid = blockIdx.x * 256 + threadIdx.x;   // 131072
    int bh = gid >> 14;
    int rem = gid & 16383;
    int vc = rem >> 5;
    int dg = rem & 31;
    float S[8];
#pragma unroll
    for (int j = 0; j < 8; ++j) S[j] = 0.f;
    size_t base = (size_t)bh * NCH * 131072 + (size_t)vc * 256 + dg * 8;
    for (int c = 0; c < NCH; ++c) {
        __hip_bfloat16* p = U + base + (size_t)c * 131072;
        bf16x8 u = *reinterpret_cast<bf16x8*>(p);
        const float* dl = &dlast[((size_t)bh * NCH + c) * HDK_ + dg * 8];
        float4 e0 = *reinterpret_cast<const float4*>(dl);
        float4 e1 = *reinterpret_cast<const float4*>(dl + 4);
        float e[8] = {e0.x, e0.y, e0.z, e0.w, e1.x, e1.y, e1.z, e1.w};
        bf16x8 outv;
#pragma unroll
        for (int j = 0; j < 8; ++j) {
            outv[j] = f2bf_bits(S[j]);
            S[j] = S[j] * e[j] + bf2f(u[j]);
        }
        *reinterpret_cast<bf16x8*>(p) = outv;
    }
}

// ---------------------------------------------------------------------------
// o_gate (fused o_pass + rms_gate): qg chunk staged ONCE (32 KB swizzled LDS,
// rule-21 pattern; dest stride FIXED: rowpair*512 shorts = 1024 B per inst).
// LDS: Av 16K + qg_l 32K + oT 64x520 bf16 (66.6K) + red 1K = ~115.6 KB.
// ---------------------------------------------------------------------------
__global__ __launch_bounds__(256) void o_gate(const __hip_bfloat16* __restrict__ qg,
                                              const __hip_bfloat16* __restrict__ U,
                                              const __hip_bfloat16* __restrict__ o1,
                                              const __hip_bfloat16* __restrict__ xg,
                                              const float* __restrict__ rms_w,
                                              __hip_bfloat16* __restrict__ gated) {
    __shared__ __align__(16) short Av[128 * 64];    // 16 KB
    __shared__ __align__(16) short qg_l[64 * 256];  // 32 KB  [t][d], granule-swizzled
    __shared__ __align__(16) short oT[64 * 520];    // 66.6 KB [t][vc], pad 8
    __shared__ float red[64][4];
    const int c = blockIdx.x, bh = blockIdx.y;
    const int b = bh >> 2, h = bh & 3;
    const int t0 = b * 2048 + c * 64;
    const int tid = threadIdx.x;
    const int wave = tid >> 6, lane = tid & 63;
    const int wr = wave >> 1, wc = wave & 1;
    const int l15 = lane & 15, kb = lane >> 4;
    const int lr8 = lane >> 3, lc8 = (lane & 7) * 8;
    const size_t Ub = ((size_t)bh * NCH + c) * 131072;

    // stage full qg chunk ONCE: 64 rows x 256 shorts; inst j covers 2 rows
    // (1024 B). linear LDS dest (rowpair*512 shorts!) + pre-swizzled source:
    // LDS granule (l&31) of row r holds global granule (l&31)^(r&7).
#pragma unroll
    for (int j = 0; j < 8; ++j) {
        int rowpair = wave * 8 + j;              // 0..31
        int row = rowpair * 2 + (lane >> 5);     // 0..63
        int gsrc = (lane & 31) ^ (row & 7);
        gl_lds16(&qg[(size_t)(t0 + row) * DKC + h * HDK_ + gsrc * 8],
                 &qg_l[rowpair * 512]);
    }

    for (int vt = 0; vt < 4; ++vt) {
        const int vc0 = vt * 128;
        f32x4 acc[4][2];
#pragma unroll
        for (int mf = 0; mf < 4; ++mf)
#pragma unroll
            for (int nf = 0; nf < 2; ++nf) acc[mf][nf] = (f32x4){0.f, 0.f, 0.f, 0.f};

        for (int ks = 0; ks < 4; ++ks) {
            const int d0 = ks * 64;
#pragma unroll
            for (int j = 0; j < 4; ++j) {
                int inst = wave * 4 + j;
                int r = inst * 8 + lr8;
                gl_lds16(&U[Ub + (size_t)(vc0 + r) * 256 + d0 + lc8], &Av[inst * 512]);
            }
            __syncthreads();
#pragma unroll
            for (int kk = 0; kk < 2; ++kk) {
                bf16x8 af[4], bfr[2];
#pragma unroll
                for (int mf = 0; mf < 4; ++mf)
                    af[mf] = *reinterpret_cast<const bf16x8*>(&Av[(wr * 64 + mf * 16 + l15) * 64 + kk * 32 + kb * 8]);
#pragma unroll
                for (int nf = 0; nf < 2; ++nf) {
                    int t = wc * 32 + nf * 16 + l15;
                    int gg = (ks * 8 + ((kk * 4 + kb) ^ (t & 7)));
                    bfr[nf] = *reinterpret_cast<const bf16x8*>(&qg_l[t * 256 + gg * 8]);
                }
#pragma unroll
                for (int mf = 0; mf < 4; ++mf)
#pragma unroll
                    for (int nf = 0; nf < 2; ++nf)
                        acc[mf][nf] = __builtin_amdgcn_mfma_f32_16x16x32_bf16(af[mf], bfr[nf], acc[mf][nf], 0, 0, 0);
            }
            __syncthreads();
        }
        // park quarter: oT[t][vc0+vc] bf16 (inter-term only)
#pragma unroll
        for (int mf = 0; mf < 4; ++mf)
#pragma unroll
            for (int nf = 0; nf < 2; ++nf)
#pragma unroll
                for (int r = 0; r < 4; ++r)
                    oT[(wc * 32 + nf * 16 + l15) * 520 + vc0 + wr * 64 + mf * 16 + kb * 4 + r] =
                        f2bf_bits(acc[mf][nf][r]);
    }
    __syncthreads();

    // pass A: o2 = bf16(oT + o1); row sums of squares
    {
        const int row = tid >> 2, q = tid & 3;
        float s = 0.f;
        const size_t gbase = (size_t)(t0 + row) * DVC + h * HDV_ + q * 128;
#pragma unroll
        for (int j = 0; j < 16; ++j) {
            bf16x8 ov = *reinterpret_cast<const bf16x8*>(&oT[row * 520 + q * 128 + j * 8]);
            bf16x8 o1v = *reinterpret_cast<const bf16x8*>(&o1[gbase + j * 8]);
            bf16x8 o2v;
#pragma unroll
            for (int e = 0; e < 8; ++e) {
                float v = bf2f(ov[e]) + bf2f(o1v[e]);
                short sb = f2bf_bits(v);
                o2v[e] = sb;
                float vb = bf2f(sb);
                s += vb * vb;
            }
            *reinterpret_cast<bf16x8*>(&oT[row * 520 + q * 128 + j * 8]) = o2v;
        }
        red[row][q] = s;
    }
    __syncthreads();

    // pass B: gated = o2 * rms * w * silu(xg), coalesced
#pragma unroll
    for (int it = 0; it < 16; ++it) {
        int idx = tid + it * 256;        // 0..4095
        int row = idx >> 6;              // 0..63
        int col8 = (idx & 63) * 8;       // 0..504
        float tot = red[row][0] + red[row][1] + red[row][2] + red[row][3];
        float rms = rsqrtf(tot * (1.f / 512.f) + 1e-5f);
        bf16x8 o2v = *reinterpret_cast<const bf16x8*>(&oT[row * 520 + col8]);
        const size_t gbase = (size_t)(t0 + row) * DVC + h * HDV_ + col8;
        bf16x8 xgv = *reinterpret_cast<const bf16x8*>(&xg[gbase]);
        float4 w0 = *reinterpret_cast<const float4*>(&rms_w[col8]);
        float4 w1 = *reinterpret_cast<const float4*>(&rms_w[col8 + 4]);
        float wv[8] = {w0.x, w0.y, w0.z, w0.w, w1.x, w1.y, w1.z, w1.w};
        bf16x8 outv;
#pragma unroll
        for (int e = 0; e < 8; ++e) {
            float gv = bf2f(xgv[e]);
            float sg = gv / (1.f + expf(-gv));
            outv[e] = f2bf_bits(bf2f(o2v[e]) * rms * wv[e] * sg);
        }
        *reinterpret_cast<bf16x8*>((short*)gated + gbase) = outv;
    }
}

// ---------------------------------------------------------------------------
extern "C" void kernel_launch(void* const* d_in, const int* in_sizes, int n_in,
                              void* d_out, int out_size, void* d_ws, size_t ws_size,
                              hipStream_t stream) {
    const float* x    = (const float*)d_in[0];
    const float* Wq   = (const float*)d_in[1];
    const float* Wk   = (const float*)d_in[2];
    const float* Wv   = (const float*)d_in[3];
    const float* Wg   = (const float*)d_in[4];
    const float* Wgk1 = (const float*)d_in[5];
    const float* Wgk2 = (const float*)d_in[6];
    const float* bgk2 = (const float*)d_in[7];
    const float* Wo   = (const float*)d_in[8];
    const float* rmsw = (const float*)d_in[9];
    float* out = (float*)d_out;
    float* ws = (float*)d_ws;

    const size_t M1 = 1ull << 20;   // floats
    __hip_bfloat16* xb    = (__hip_bfloat16*)ws;              // [0,2M)   8 MB
    __hip_bfloat16* WtAll = (__hip_bfloat16*)(ws + 2 * M1);   // [2M,5M)  12 MB
    __hip_bfloat16* q_b   = (__hip_bfloat16*)(ws + 5 * M1);   // [5M,7M)  8 MB
    __hip_bfloat16* k_b   = (__hip_bfloat16*)(ws + 7 * M1);   // [7M,9M)  8 MB
    float*          g     = ws + 13 * M1;                     // [13M,17M) 16 MB
    __hip_bfloat16* U     = (__hip_bfloat16*)ws;              // [0,16M) 64 MB overlay
    __hip_bfloat16* xg_b  = (__hip_bfloat16*)(ws + 17 * M1);  // [17M,21M) 16 MB
    __hip_bfloat16* qgb   = (__hip_bfloat16*)(ws + 21 * M1);  // [21M,23M) 8 MB
    __hip_bfloat16* vT    = (__hip_bfloat16*)(ws + 25 * M1);  // [25M,29M) 16 MB
    __hip_bfloat16* o1    = (__hip_bfloat16*)(ws + 29 * M1);  // [29M,33M) 16 MB
    float*          dlast = ws + 37 * M1 + 65536;             // 256 KB
    __hip_bfloat16* WtO   = (__hip_bfloat16*)(ws + 38 * M1);  // [38M,39M) 4 MB
    __hip_bfloat16* gated = (__hip_bfloat16*)(ws + 25 * M1);  // over vT (dead after gla_chunk)

    prep_all<<<12288, 256, 0, stream>>>(Wq, Wk, Wv, Wg, Wo, WtAll, WtO,
                                        x, Wgk1, Wgk2, bgk2, xb, g);

    gemm256<<<dim3(24, 32), 512, 0, stream>>>(xb, WtAll, q_b, k_b, vT, xg_b);

    gla_chunk<<<dim3(NCH, 8), 256, 0, stream>>>(q_b, k_b, vT, g, qgb, U, o1, dlast);

    scan_pass<<<512, 256, 0, stream>>>(U, dlast);
    o_gate<<<dim3(NCH, 8), 256, 0, stream>>>(qgb, U, o1, xg_b, rmsw, gated);

    gemm_bf16<<<dim3(8, 32), 256, 0, stream>>>(gated, WtO, out, TOK, DM, DVC);
}